// Round 1
// baseline (580.268 us; speedup 1.0000x reference)
//
#include <hip/hip_runtime.h>
#include <math.h>

#define B_  128
#define E_  128
#define H2_ 512
#define H3_ 1536
#define L_  512
#define V_  50000
#define VL_ 50512   // V + L

// ---------------- embedding gather ----------------
__global__ void k_embed(const int* __restrict__ ids, const float* __restrict__ tab,
                        float* __restrict__ emb) {
    int idx = blockIdx.x * blockDim.x + threadIdx.x;   // B*E = 16384
    int b = idx >> 7, e = idx & 127;
    emb[idx] = tab[(size_t)ids[b] * E_ + e];
}

// ---------------- generic tiled GEMM: C[m,n] = sum_k A[m,k]*W[n,k] + bias[n] ----------------
// block 256 threads, 64x64 tile, BK=16, thread tile 4x4
__global__ void gemm_atw(const float* __restrict__ A, int lda,
                         const float* __restrict__ W, int ldw,
                         const float* __restrict__ bias,
                         float* __restrict__ C, int ldc,
                         int M, int N, int K) {
    __shared__ float As[64][17];
    __shared__ float Ws[64][17];
    int bm = blockIdx.x * 64;
    int bn = blockIdx.y * 64;
    int tid = threadIdx.x;
    int tm = (tid >> 4) << 2;
    int tn = (tid & 15) << 2;
    float acc[4][4] = {};
    for (int k0 = 0; k0 < K; k0 += 16) {
        for (int i = tid; i < 64 * 16; i += 256) {
            int m = i >> 4, k = i & 15;
            int gm = bm + m;
            As[m][k] = (gm < M) ? A[(size_t)gm * lda + k0 + k] : 0.f;
        }
        for (int i = tid; i < 64 * 16; i += 256) {
            int n = i >> 4, k = i & 15;
            int gn = bn + n;
            Ws[n][k] = (gn < N) ? W[(size_t)gn * ldw + k0 + k] : 0.f;
        }
        __syncthreads();
        #pragma unroll
        for (int k = 0; k < 16; ++k) {
            float a[4], w[4];
            #pragma unroll
            for (int i = 0; i < 4; ++i) a[i] = As[tm + i][k];
            #pragma unroll
            for (int j = 0; j < 4; ++j) w[j] = Ws[tn + j][k];
            #pragma unroll
            for (int i = 0; i < 4; ++i)
                #pragma unroll
                for (int j = 0; j < 4; ++j)
                    acc[i][j] += a[i] * w[j];
        }
        __syncthreads();
    }
    for (int i = 0; i < 4; ++i) {
        int gm = bm + tm + i;
        if (gm >= M) continue;
        for (int j = 0; j < 4; ++j) {
            int gn = bn + tn + j;
            if (gn >= N) continue;
            C[(size_t)gm * ldc + gn] = acc[i][j] + (bias ? bias[gn] : 0.f);
        }
    }
}

// ---------------- GRU gates ----------------
__global__ void k_gru(const float* __restrict__ gx, const float* __restrict__ gh,
                      const float* __restrict__ h0, float* __restrict__ comb,
                      float* __restrict__ hout) {
    int idx = blockIdx.x * blockDim.x + threadIdx.x;  // B*H2 = 65536
    int b = idx >> 9, h = idx & 511;
    const float* gxb = gx + b * H3_;
    const float* ghb = gh + b * H3_;
    float xr = gxb[h], xz = gxb[H2_ + h], xn = gxb[2 * H2_ + h];
    float hr = ghb[h], hz = ghb[H2_ + h], hn = ghb[2 * H2_ + h];
    float r = 1.f / (1.f + expf(-(xr + hr)));
    float z = 1.f / (1.f + expf(-(xz + hz)));
    float n = tanhf(xn + r * hn);
    float hv = (1.f - z) * n + z * h0[idx];
    comb[b * (2 * H2_) + h] = hv;   // combined[:, 0:512] = h_new
    hout[idx] = hv;                 // d_out h_new
}

// ---------------- attention scores: one wave per (l,b) ----------------
__global__ void k_scores(const float* __restrict__ enc, const float* __restrict__ dsl,
                         const float* __restrict__ w_h, const float* __restrict__ att_v,
                         float* __restrict__ scores) {
    int wid = (blockIdx.x << 2) + (threadIdx.x >> 6);
    int lane = threadIdx.x & 63;
    int l = wid >> 7, b = wid & 127;
    const float4* e4 = (const float4*)(enc + ((size_t)(l * B_ + b)) * H2_);
    const float4* d4 = (const float4*)(dsl + b * H2_);
    const float4* w4 = (const float4*)w_h;
    const float4* v4 = (const float4*)att_v;
    float s = 0.f;
    #pragma unroll
    for (int i = 0; i < 2; ++i) {
        int j = lane + (i << 6);
        float4 e = e4[j], d = d4[j], w = w4[j], v = v4[j];
        s += v.x * tanhf(w.x * e.x + d.x);
        s += v.y * tanhf(w.y * e.y + d.y);
        s += v.z * tanhf(w.z * e.z + d.z);
        s += v.w * tanhf(w.w * e.w + d.w);
    }
    #pragma unroll
    for (int o = 32; o; o >>= 1) s += __shfl_xor(s, o);
    if (lane == 0) scores[l * B_ + b] = s;
}

// ---------------- softmax over batch axis (per l) ----------------
__global__ void k_softmax(const float* __restrict__ scores, float* __restrict__ attn) {
    int l = blockIdx.x, lane = threadIdx.x;   // 64 threads
    float s0 = scores[l * B_ + lane], s1 = scores[l * B_ + lane + 64];
    float m = fmaxf(s0, s1);
    #pragma unroll
    for (int o = 32; o; o >>= 1) m = fmaxf(m, __shfl_xor(m, o));
    float e0 = expf(s0 - m), e1 = expf(s1 - m);
    float t = e0 + e1;
    #pragma unroll
    for (int o = 32; o; o >>= 1) t += __shfl_xor(t, o);
    float inv = 1.f / t;
    attn[l * B_ + lane] = e0 * inv;
    attn[l * B_ + lane + 64] = e1 * inv;
}

// ---------------- zero context slots of combined ----------------
__global__ void k_zero_ctx(float* __restrict__ comb) {
    int idx = blockIdx.x * blockDim.x + threadIdx.x;  // 65536
    int b = idx >> 9, h = idx & 511;
    comb[b * (2 * H2_) + H2_ + h] = 0.f;
}

// ---------------- context: block (b, l-chunk of 64), 512 threads over h ----------------
__global__ void k_context(const float* __restrict__ enc, const float* __restrict__ attn,
                          float* __restrict__ comb) {
    int b = blockIdx.x, h = threadIdx.x;
    int l0 = blockIdx.y << 6;
    __shared__ float a_s[64];
    if (threadIdx.x < 64) a_s[threadIdx.x] = attn[(l0 + threadIdx.x) * B_ + b];
    __syncthreads();
    const float* e = enc + ((size_t)l0 * B_ + b) * H2_ + h;
    float c = 0.f;
    #pragma unroll 8
    for (int i = 0; i < 64; ++i) c += a_s[i] * e[(size_t)i * B_ * H2_];
    atomicAdd(&comb[b * (2 * H2_) + H2_ + h], c);
}

// ---------------- p_gen: one wave per b ----------------
__global__ void k_pgen(const float* __restrict__ comb, const float* __restrict__ emb,
                       const float* __restrict__ W_ptr, const float* __restrict__ b_ptr,
                       float* __restrict__ pgen) {
    int b = blockIdx.x, lane = threadIdx.x;  // 64 threads
    float s = 0.f;
    for (int j = lane; j < 2 * H2_; j += 64) s += W_ptr[j] * comb[b * (2 * H2_) + j];
    for (int j = lane; j < E_; j += 64) s += W_ptr[2 * H2_ + j] * emb[b * E_ + j];
    #pragma unroll
    for (int o = 32; o; o >>= 1) s += __shfl_xor(s, o);
    if (lane == 0) pgen[b] = 1.f / (1.f + expf(-(s + b_ptr[0])));
}

// ---------------- per-row online max/sum over logits ----------------
__global__ void k_rowstat(const float* __restrict__ out, float* __restrict__ rmax,
                          float* __restrict__ rsum) {
    int b = blockIdx.x, tid = threadIdx.x;  // 256 threads
    const float* row = out + (size_t)b * VL_;
    float m = -1e30f, s = 0.f;
    for (int j = tid; j < V_; j += 256) {
        float x = row[j];
        if (x > m) { s = s * expf(m - x) + 1.f; m = x; }
        else s += expf(x - m);
    }
    __shared__ float sm[256], ss[256];
    sm[tid] = m; ss[tid] = s;
    __syncthreads();
    for (int st = 128; st; st >>= 1) {
        if (tid < st) {
            float m2 = sm[tid + st], s2 = ss[tid + st];
            float mm = fmaxf(sm[tid], m2);
            ss[tid] = ss[tid] * expf(sm[tid] - mm) + s2 * expf(m2 - mm);
            sm[tid] = mm;
        }
        __syncthreads();
    }
    if (tid == 0) { rmax[b] = sm[0]; rsum[b] = ss[0]; }
}

// ---------------- finalize p_final = p_gen * softmax(logits), pad zeros ----------------
__global__ void k_final(float* __restrict__ out, const float* __restrict__ pgen,
                        const float* __restrict__ rmax, const float* __restrict__ rsum) {
    int idx = blockIdx.x * blockDim.x + threadIdx.x;
    if (idx >= B_ * VL_) return;
    int b = idx / VL_;
    int j = idx - b * VL_;
    float v = 0.f;
    if (j < V_) v = pgen[b] * expf(out[idx] - rmax[b]) / rsum[b];
    out[idx] = v;
}

// ---------------- scatter copy distribution ----------------
__global__ void k_scatter(float* __restrict__ out, const int* __restrict__ full_input,
                          const float* __restrict__ attn, const float* __restrict__ pgen) {
    int idx = blockIdx.x * blockDim.x + threadIdx.x;  // L*B = 65536
    int b = idx & 127;
    int tok = full_input[idx];
    atomicAdd(&out[(size_t)b * VL_ + tok], (1.f - pgen[b]) * attn[idx]);
}

extern "C" void kernel_launch(void* const* d_in, const int* in_sizes, int n_in,
                              void* d_out, int out_size, void* d_ws, size_t ws_size,
                              hipStream_t stream) {
    const int*   input_ids = (const int*)d_in[0];
    const float* hidden    = (const float*)d_in[1];
    const float* enc       = (const float*)d_in[2];
    const int*   full_in   = (const int*)d_in[3];
    const float* emb_tab   = (const float*)d_in[4];
    const float* W_ih      = (const float*)d_in[5];
    const float* W_hh      = (const float*)d_in[6];
    const float* b_ih      = (const float*)d_in[7];
    const float* b_hh      = (const float*)d_in[8];
    const float* W_ds      = (const float*)d_in[9];
    const float* b_ds      = (const float*)d_in[10];
    const float* w_h       = (const float*)d_in[11];
    const float* att_v     = (const float*)d_in[12];
    const float* W_oh      = (const float*)d_in[13];
    const float* b_oh      = (const float*)d_in[14];
    const float* W_ov      = (const float*)d_in[15];
    const float* b_ov      = (const float*)d_in[16];
    const float* W_ptr     = (const float*)d_in[17];
    const float* b_ptr     = (const float*)d_in[18];

    float* out = (float*)d_out;
    float* p_final = out;                                  // [B, VL]
    float* h_out   = out + (size_t)B_ * VL_;               // [B, H2]
    float* attn    = out + (size_t)B_ * VL_ + B_ * H2_;    // [L, B]

    float* ws = (float*)d_ws;
    float* emb    = ws;            // 16384
    float* gx     = emb + 16384;   // 196608
    float* gh     = gx + 196608;   // 196608
    float* comb   = gh + 196608;   // 131072  [B, 2*H2]: h_new | context
    float* dsl    = comb + 131072; // 65536
    float* scores = dsl + 65536;   // 65536
    float* hid    = scores + 65536;// 16384
    float* pgen   = hid + 16384;   // 128
    float* rmax   = pgen + 128;    // 128
    float* rsum   = rmax + 128;    // 128

    // 1. embedding gather
    k_embed<<<dim3(64), dim3(256), 0, stream>>>(input_ids, emb_tab, emb);
    // 2. gx = emb @ W_ih^T + b_ih   [128,1536] K=128
    gemm_atw<<<dim3(2, 24), dim3(256), 0, stream>>>(emb, E_, W_ih, E_, b_ih, gx, H3_, B_, H3_, E_);
    // 3. gh = h0 @ W_hh^T + b_hh    [128,1536] K=512
    gemm_atw<<<dim3(2, 24), dim3(256), 0, stream>>>(hidden, H2_, W_hh, H2_, b_hh, gh, H3_, B_, H3_, H2_);
    // 4. GRU gates -> h_new (into comb[:,0:512] and d_out)
    k_gru<<<dim3(256), dim3(256), 0, stream>>>(gx, gh, hidden, comb, h_out);
    // 5. dsl = h_new @ W_ds^T + b_ds  [128,512] K=512
    gemm_atw<<<dim3(2, 8), dim3(256), 0, stream>>>(comb, 2 * H2_, W_ds, H2_, b_ds, dsl, H2_, B_, H2_, H2_);
    // 6. attention scores [L,B]
    k_scores<<<dim3(L_ * B_ / 4), dim3(256), 0, stream>>>(enc, dsl, w_h, att_v, scores);
    // 7. softmax over batch axis -> attn (d_out)
    k_softmax<<<dim3(L_), dim3(64), 0, stream>>>(scores, attn);
    // 8. context = sum_l attn[l,b] * enc[l,b,:]  (into comb[:,512:1024])
    k_zero_ctx<<<dim3(256), dim3(256), 0, stream>>>(comb);
    k_context<<<dim3(B_, 8), dim3(512), 0, stream>>>(enc, attn, comb);
    // 9. p_gen
    k_pgen<<<dim3(B_), dim3(64), 0, stream>>>(comb, emb, W_ptr, b_ptr, pgen);
    // 10. hid = comb @ W_oh^T + b_oh  [128,128] K=1024
    gemm_atw<<<dim3(2, 2), dim3(256), 0, stream>>>(comb, 2 * H2_, W_oh, 2 * H2_, b_oh, hid, E_, B_, E_, 2 * H2_);
    // 11. logits = hid @ W_ov^T + b_ov -> written into p_final region (ldc = VL)
    gemm_atw<<<dim3(2, 782), dim3(256), 0, stream>>>(hid, E_, W_ov, E_, b_ov, p_final, VL_, B_, V_, E_);
    // 12. per-row softmax stats over logits
    k_rowstat<<<dim3(B_), dim3(256), 0, stream>>>(p_final, rmax, rsum);
    // 13. finalize p_vocab * p_gen (+ zero pad region), in place
    k_final<<<dim3((B_ * VL_ + 255) / 256), dim3(256), 0, stream>>>(p_final, pgen, rmax, rsum);
    // 14. scatter (1-p_gen)*attn onto extended vocab
    k_scatter<<<dim3(L_ * B_ / 256), dim3(256), 0, stream>>>(p_final, full_in, attn, pgen);
}

// Round 2
// 204.364 us; speedup vs baseline: 2.8394x; 2.8394x over previous
//
#include <hip/hip_runtime.h>
#include <math.h>

#define B_  128
#define E_  128
#define H2_ 512
#define H3_ 1536
#define L_  512
#define V_  50000
#define VL_ 50512   // V + L

__device__ __forceinline__ float fast_tanh(float x) {
    float e = __expf(2.f * x);
    return 1.f - 2.f / (e + 1.f);
}
__device__ __forceinline__ float fast_sigmoid(float x) {
    return 1.f / (1.f + __expf(-x));
}

// ---------------- generic tiled GEMM: C[m,n] = sum_k A[m,k]*W[n,k] (+bias) ----------------
// 256 threads. k-major LDS. Optional A-row gather (embedding). Optional split-K (atomicAdd).
// M is always a multiple of BM here (no M guards). N guarded.
template<int BM, int BN, int BK, int TM, int TN, bool GATHER, int SPLITK>
__global__ void gemm_t(const float* __restrict__ A, int lda,
                       const int* __restrict__ ids, const float* __restrict__ tab,
                       const float* __restrict__ W, int ldw,
                       const float* __restrict__ bias,
                       float* __restrict__ C, int ldc,
                       int N, int K) {
    constexpr int PAD = 4;
    __shared__ float As[BK][BM + PAD];
    __shared__ float Ws[BK][BN + PAD];
    int bm = blockIdx.x * BM, bn = blockIdx.y * BN;
    int tid = threadIdx.x;
    constexpr int NT = BN / TN;
    int tm0 = (tid / NT) * TM;
    int tn0 = (tid % NT) * TN;
    int kchunk = K / SPLITK;
    int kbeg = blockIdx.z * kchunk;
    float acc[TM][TN] = {};
    for (int k0 = kbeg; k0 < kbeg + kchunk; k0 += BK) {
        constexpr int AV = BM * BK / 4;
        #pragma unroll
        for (int v = tid; v < AV; v += 256) {
            int m = v / (BK / 4), q = (v % (BK / 4)) * 4;
            int gm = bm + m;
            const float* arow = GATHER ? (tab + (size_t)ids[gm] * lda)
                                       : (A + (size_t)gm * lda);
            float4 x = *(const float4*)(arow + k0 + q);
            As[q + 0][m] = x.x; As[q + 1][m] = x.y;
            As[q + 2][m] = x.z; As[q + 3][m] = x.w;
        }
        constexpr int WV = BN * BK / 4;
        #pragma unroll
        for (int v = tid; v < WV; v += 256) {
            int n = v / (BK / 4), q = (v % (BK / 4)) * 4;
            int gn = bn + n;
            float4 x = make_float4(0.f, 0.f, 0.f, 0.f);
            if (gn < N) x = *(const float4*)(W + (size_t)gn * ldw + k0 + q);
            Ws[q + 0][n] = x.x; Ws[q + 1][n] = x.y;
            Ws[q + 2][n] = x.z; Ws[q + 3][n] = x.w;
        }
        __syncthreads();
        #pragma unroll
        for (int kk = 0; kk < BK; ++kk) {
            float a[TM], w[TN];
            #pragma unroll
            for (int i = 0; i < TM; ++i) a[i] = As[kk][tm0 + i];
            #pragma unroll
            for (int j = 0; j < TN; ++j) w[j] = Ws[kk][tn0 + j];
            #pragma unroll
            for (int i = 0; i < TM; ++i)
                #pragma unroll
                for (int j = 0; j < TN; ++j) acc[i][j] += a[i] * w[j];
        }
        __syncthreads();
    }
    #pragma unroll
    for (int i = 0; i < TM; ++i) {
        int gm = bm + tm0 + i;
        #pragma unroll
        for (int j = 0; j < TN; ++j) {
            int gn = bn + tn0 + j;
            if (gn >= N) continue;
            if (SPLITK == 1)
                C[(size_t)gm * ldc + gn] = acc[i][j] + (bias ? bias[gn] : 0.f);
            else
                atomicAdd(&C[(size_t)gm * ldc + gn], acc[i][j]);
        }
    }
}

// ---------------- bias broadcast init (for split-K target) ----------------
__global__ void k_init_bias(float* __restrict__ C, const float* __restrict__ bias) {
    int idx = blockIdx.x * blockDim.x + threadIdx.x;   // B*E = 16384
    C[idx] = bias[idx & 127];
}

// ---------------- GRU gates ----------------
__global__ void k_gru(const float* __restrict__ gx, const float* __restrict__ gh,
                      const float* __restrict__ h0, float* __restrict__ comb,
                      float* __restrict__ hout) {
    int idx = blockIdx.x * blockDim.x + threadIdx.x;  // B*H2 = 65536
    int b = idx >> 9, h = idx & 511;
    const float* gxb = gx + b * H3_;
    const float* ghb = gh + b * H3_;
    float xr = gxb[h], xz = gxb[H2_ + h], xn = gxb[2 * H2_ + h];
    float hr = ghb[h], hz = ghb[H2_ + h], hn = ghb[2 * H2_ + h];
    float r = fast_sigmoid(xr + hr);
    float z = fast_sigmoid(xz + hz);
    float n = fast_tanh(xn + r * hn);
    float hv = (1.f - z) * n + z * h0[idx];
    comb[b * (2 * H2_) + h] = hv;
    hout[idx] = hv;
}

// ---------------- attention scores: one wave per (l,b) ----------------
__global__ void k_scores(const float* __restrict__ enc, const float* __restrict__ dsl,
                         const float* __restrict__ w_h, const float* __restrict__ att_v,
                         float* __restrict__ scores) {
    int wid = (blockIdx.x << 2) + (threadIdx.x >> 6);
    int lane = threadIdx.x & 63;
    int l = wid >> 7, b = wid & 127;
    const float4* e4 = (const float4*)(enc + ((size_t)(l * B_ + b)) * H2_);
    const float4* d4 = (const float4*)(dsl + b * H2_);
    const float4* w4 = (const float4*)w_h;
    const float4* v4 = (const float4*)att_v;
    float s = 0.f;
    #pragma unroll
    for (int i = 0; i < 2; ++i) {
        int j = lane + (i << 6);
        float4 e = e4[j], d = d4[j], w = w4[j], v = v4[j];
        s += v.x * fast_tanh(w.x * e.x + d.x);
        s += v.y * fast_tanh(w.y * e.y + d.y);
        s += v.z * fast_tanh(w.z * e.z + d.z);
        s += v.w * fast_tanh(w.w * e.w + d.w);
    }
    #pragma unroll
    for (int o = 32; o; o >>= 1) s += __shfl_xor(s, o);
    if (lane == 0) scores[l * B_ + b] = s;
}

// ---------------- softmax over batch axis (per l) ----------------
__global__ void k_softmax(const float* __restrict__ scores, float* __restrict__ attn) {
    int l = blockIdx.x, lane = threadIdx.x;   // 64 threads
    float s0 = scores[l * B_ + lane], s1 = scores[l * B_ + lane + 64];
    float m = fmaxf(s0, s1);
    #pragma unroll
    for (int o = 32; o; o >>= 1) m = fmaxf(m, __shfl_xor(m, o));
    float e0 = __expf(s0 - m), e1 = __expf(s1 - m);
    float t = e0 + e1;
    #pragma unroll
    for (int o = 32; o; o >>= 1) t += __shfl_xor(t, o);
    float inv = 1.f / t;
    attn[l * B_ + lane] = e0 * inv;
    attn[l * B_ + lane + 64] = e1 * inv;
}

// ---------------- zero context slots of combined ----------------
__global__ void k_zero_ctx(float* __restrict__ comb) {
    int idx = blockIdx.x * blockDim.x + threadIdx.x;  // 65536
    int b = idx >> 9, h = idx & 511;
    comb[b * (2 * H2_) + H2_ + h] = 0.f;
}

// ---------------- context: block (b, l-chunk of 64), 512 threads over h ----------------
__global__ void k_context(const float* __restrict__ enc, const float* __restrict__ attn,
                          float* __restrict__ comb) {
    int b = blockIdx.x, h = threadIdx.x;
    int l0 = blockIdx.y << 6;
    __shared__ float a_s[64];
    if (threadIdx.x < 64) a_s[threadIdx.x] = attn[(l0 + threadIdx.x) * B_ + b];
    __syncthreads();
    const float* e = enc + ((size_t)l0 * B_ + b) * H2_ + h;
    float c = 0.f;
    #pragma unroll 8
    for (int i = 0; i < 64; ++i) c += a_s[i] * e[(size_t)i * B_ * H2_];
    atomicAdd(&comb[b * (2 * H2_) + H2_ + h], c);
}

// ---------------- p_gen: one wave per b (emb gathered directly) ----------------
__global__ void k_pgen(const float* __restrict__ comb,
                       const int* __restrict__ ids, const float* __restrict__ tab,
                       const float* __restrict__ W_ptr, const float* __restrict__ b_ptr,
                       float* __restrict__ pgen) {
    int b = blockIdx.x, lane = threadIdx.x;  // 64 threads
    float s = 0.f;
    for (int j = lane; j < 2 * H2_; j += 64) s += W_ptr[j] * comb[b * (2 * H2_) + j];
    const float* erow = tab + (size_t)ids[b] * E_;
    for (int j = lane; j < E_; j += 64) s += W_ptr[2 * H2_ + j] * erow[j];
    #pragma unroll
    for (int o = 32; o; o >>= 1) s += __shfl_xor(s, o);
    if (lane == 0) pgen[b] = fast_sigmoid(s + b_ptr[0]);
}

// ---------------- per-row online max/sum over logits (float4) ----------------
__global__ void k_rowstat(const float* __restrict__ out, float* __restrict__ rmax,
                          float* __restrict__ rsum) {
    int b = blockIdx.x, tid = threadIdx.x;  // 256 threads
    const float4* row = (const float4*)(out + (size_t)b * VL_);
    float m = -1e30f, s = 0.f;
    for (int j = tid; j < V_ / 4; j += 256) {
        float4 x = row[j];
        float m2 = fmaxf(fmaxf(x.x, x.y), fmaxf(x.z, x.w));
        if (m2 > m) { s *= __expf(m - m2); m = m2; }
        s += __expf(x.x - m) + __expf(x.y - m) + __expf(x.z - m) + __expf(x.w - m);
    }
    __shared__ float sm[256], ss[256];
    sm[tid] = m; ss[tid] = s;
    __syncthreads();
    for (int st = 128; st; st >>= 1) {
        if (tid < st) {
            float m2 = sm[tid + st], s2 = ss[tid + st];
            float mm = fmaxf(sm[tid], m2);
            ss[tid] = ss[tid] * __expf(sm[tid] - mm) + s2 * __expf(m2 - mm);
            sm[tid] = mm;
        }
        __syncthreads();
    }
    if (tid == 0) { rmax[b] = sm[0]; rsum[b] = ss[0]; }
}

// ---------------- finalize p_final = p_gen * softmax(logits), pad zeros (float4) -------
__global__ void k_final(float* __restrict__ out, const float* __restrict__ pgen,
                        const float* __restrict__ rmax, const float* __restrict__ rsum) {
    int idx = blockIdx.x * blockDim.x + threadIdx.x;   // B * VL/4 = 1616384
    if (idx >= B_ * (VL_ / 4)) return;
    int b = idx / (VL_ / 4);
    int j = idx - b * (VL_ / 4);
    float4* p = (float4*)(out) + idx;
    float4 v = make_float4(0.f, 0.f, 0.f, 0.f);
    if (j < V_ / 4) {   // V_ % 4 == 0: float4 fully in-vocab
        float4 x = *p;
        float sc = pgen[b] / rsum[b], m = rmax[b];
        v.x = sc * __expf(x.x - m); v.y = sc * __expf(x.y - m);
        v.z = sc * __expf(x.z - m); v.w = sc * __expf(x.w - m);
    }
    *p = v;
}

// ---------------- scatter copy distribution ----------------
__global__ void k_scatter(float* __restrict__ out, const int* __restrict__ full_input,
                          const float* __restrict__ attn, const float* __restrict__ pgen) {
    int idx = blockIdx.x * blockDim.x + threadIdx.x;  // L*B = 65536
    int b = idx & 127;
    int tok = full_input[idx];
    atomicAdd(&out[(size_t)b * VL_ + tok], (1.f - pgen[b]) * attn[idx]);
}

extern "C" void kernel_launch(void* const* d_in, const int* in_sizes, int n_in,
                              void* d_out, int out_size, void* d_ws, size_t ws_size,
                              hipStream_t stream) {
    const int*   input_ids = (const int*)d_in[0];
    const float* hidden    = (const float*)d_in[1];
    const float* enc       = (const float*)d_in[2];
    const int*   full_in   = (const int*)d_in[3];
    const float* emb_tab   = (const float*)d_in[4];
    const float* W_ih      = (const float*)d_in[5];
    const float* W_hh      = (const float*)d_in[6];
    const float* b_ih      = (const float*)d_in[7];
    const float* b_hh      = (const float*)d_in[8];
    const float* W_ds      = (const float*)d_in[9];
    const float* b_ds      = (const float*)d_in[10];
    const float* w_h       = (const float*)d_in[11];
    const float* att_v     = (const float*)d_in[12];
    const float* W_oh      = (const float*)d_in[13];
    const float* b_oh      = (const float*)d_in[14];
    const float* W_ov      = (const float*)d_in[15];
    const float* b_ov      = (const float*)d_in[16];
    const float* W_ptr     = (const float*)d_in[17];
    const float* b_ptr     = (const float*)d_in[18];

    float* out = (float*)d_out;
    float* p_final = out;                                  // [B, VL]
    float* h_out   = out + (size_t)B_ * VL_;               // [B, H2]
    float* attn    = out + (size_t)B_ * VL_ + B_ * H2_;    // [L, B]

    float* ws = (float*)d_ws;
    float* gx     = ws;            // 196608
    float* gh     = gx + 196608;   // 196608
    float* comb   = gh + 196608;   // 131072  [B, 2*H2]: h_new | context
    float* dsl    = comb + 131072; // 65536
    float* scores = dsl + 65536;   // 65536
    float* hid    = scores + 65536;// 16384
    float* pgen   = hid + 16384;   // 128
    float* rmax   = pgen + 128;    // 128
    float* rsum   = rmax + 128;    // 128

    // 1. gx = emb[ids] @ W_ih^T + b_ih   [128,1536] K=128 (embedding gather fused)
    gemm_t<32,32,32,2,2,true,1><<<dim3(4,48), dim3(256), 0, stream>>>(
        nullptr, E_, input_ids, emb_tab, W_ih, E_, b_ih, gx, H3_, H3_, E_);
    // 2. gh = h0 @ W_hh^T + b_hh        [128,1536] K=512
    gemm_t<32,32,32,2,2,false,1><<<dim3(4,48), dim3(256), 0, stream>>>(
        hidden, H2_, nullptr, nullptr, W_hh, H2_, b_hh, gh, H3_, H3_, H2_);
    // 3. GRU gates -> h_new
    k_gru<<<dim3(256), dim3(256), 0, stream>>>(gx, gh, hidden, comb, h_out);
    // 4. dsl = h_new @ W_ds^T + b_ds    [128,512] K=512
    gemm_t<32,32,32,2,2,false,1><<<dim3(4,16), dim3(256), 0, stream>>>(
        comb, 2*H2_, nullptr, nullptr, W_ds, H2_, b_ds, dsl, H2_, H2_, H2_);
    // 5. attention scores
    k_scores<<<dim3(L_*B_/4), dim3(256), 0, stream>>>(enc, dsl, w_h, att_v, scores);
    // 6. softmax over batch axis
    k_softmax<<<dim3(L_), dim3(64), 0, stream>>>(scores, attn);
    // 7. context
    k_zero_ctx<<<dim3(256), dim3(256), 0, stream>>>(comb);
    k_context<<<dim3(B_, 8), dim3(512), 0, stream>>>(enc, attn, comb);
    // 8. p_gen
    k_pgen<<<dim3(B_), dim3(64), 0, stream>>>(comb, input_ids, emb_tab, W_ptr, b_ptr, pgen);
    // 9. hid = comb @ W_oh^T + b_oh     [128,128] K=1024, split-K 8
    k_init_bias<<<dim3(64), dim3(256), 0, stream>>>(hid, b_oh);
    gemm_t<32,32,32,2,2,false,8><<<dim3(4,4,8), dim3(256), 0, stream>>>(
        comb, 2*H2_, nullptr, nullptr, W_oh, 2*H2_, nullptr, hid, E_, E_, 2*H2_);
    // 10. logits = hid @ W_ov^T + b_ov -> p_final region (ldc = VL)
    gemm_t<64,128,32,4,8,false,1><<<dim3(2,391), dim3(256), 0, stream>>>(
        hid, E_, nullptr, nullptr, W_ov, E_, b_ov, p_final, VL_, V_, E_);
    // 11. softmax stats
    k_rowstat<<<dim3(B_), dim3(256), 0, stream>>>(p_final, rmax, rsum);
    // 12. finalize
    k_final<<<dim3((B_*(VL_/4) + 255)/256), dim3(256), 0, stream>>>(p_final, pgen, rmax, rsum);
    // 13. scatter
    k_scatter<<<dim3(L_*B_/256), dim3(256), 0, stream>>>(p_final, full_in, attn, pgen);
}

// Round 4
// 200.034 us; speedup vs baseline: 2.9009x; 1.0216x over previous
//
#include <hip/hip_runtime.h>
#include <math.h>

#define B_  128
#define E_  128
#define H2_ 512
#define H3_ 1536
#define L_  512
#define V_  50000
#define VL_ 50512   // V + L

__device__ __forceinline__ float fast_tanh(float x) {
    float e = __expf(2.f * x);
    return 1.f - 2.f / (e + 1.f);
}
__device__ __forceinline__ float fast_sigmoid(float x) {
    return 1.f / (1.f + __expf(-x));
}

// ---------------- generic tiled GEMM: C[m,n] = sum_k A[m,k]*W[n,k] (+bias) ----------------
// 256 threads. k-major LDS. Optional A-row gather (embedding). Optional split-K (atomicAdd).
template<int BM, int BN, int BK, int TM, int TN, bool GATHER, int SPLITK>
__global__ void gemm_t(const float* __restrict__ A, int lda,
                       const int* __restrict__ ids, const float* __restrict__ tab,
                       const float* __restrict__ W, int ldw,
                       const float* __restrict__ bias,
                       float* __restrict__ C, int ldc,
                       int N, int K) {
    constexpr int PAD = 4;
    __shared__ float As[BK][BM + PAD];
    __shared__ float Ws[BK][BN + PAD];
    int bm = blockIdx.x * BM, bn = blockIdx.y * BN;
    int tid = threadIdx.x;
    constexpr int NT = BN / TN;
    int tm0 = (tid / NT) * TM;
    int tn0 = (tid % NT) * TN;
    int kchunk = K / SPLITK;
    int kbeg = blockIdx.z * kchunk;
    float acc[TM][TN] = {};
    for (int k0 = kbeg; k0 < kbeg + kchunk; k0 += BK) {
        constexpr int AV = BM * BK / 4;
        #pragma unroll
        for (int v = tid; v < AV; v += 256) {
            int m = v / (BK / 4), q = (v % (BK / 4)) * 4;
            int gm = bm + m;
            const float* arow = GATHER ? (tab + (size_t)ids[gm] * lda)
                                       : (A + (size_t)gm * lda);
            float4 x = *(const float4*)(arow + k0 + q);
            As[q + 0][m] = x.x; As[q + 1][m] = x.y;
            As[q + 2][m] = x.z; As[q + 3][m] = x.w;
        }
        constexpr int WV = BN * BK / 4;
        #pragma unroll
        for (int v = tid; v < WV; v += 256) {
            int n = v / (BK / 4), q = (v % (BK / 4)) * 4;
            int gn = bn + n;
            float4 x = make_float4(0.f, 0.f, 0.f, 0.f);
            if (gn < N) x = *(const float4*)(W + (size_t)gn * ldw + k0 + q);
            Ws[q + 0][n] = x.x; Ws[q + 1][n] = x.y;
            Ws[q + 2][n] = x.z; Ws[q + 3][n] = x.w;
        }
        __syncthreads();
        #pragma unroll
        for (int kk = 0; kk < BK; ++kk) {
            float a[TM], w[TN];
            #pragma unroll
            for (int i = 0; i < TM; ++i) a[i] = As[kk][tm0 + i];
            #pragma unroll
            for (int j = 0; j < TN; ++j) w[j] = Ws[kk][tn0 + j];
            #pragma unroll
            for (int i = 0; i < TM; ++i)
                #pragma unroll
                for (int j = 0; j < TN; ++j) acc[i][j] += a[i] * w[j];
        }
        __syncthreads();
    }
    #pragma unroll
    for (int i = 0; i < TM; ++i) {
        int gm = bm + tm0 + i;
        #pragma unroll
        for (int j = 0; j < TN; ++j) {
            int gn = bn + tn0 + j;
            if (gn >= N) continue;
            if (SPLITK == 1)
                C[(size_t)gm * ldc + gn] = acc[i][j] + (bias ? bias[gn] : 0.f);
            else
                atomicAdd(&C[(size_t)gm * ldc + gn], acc[i][j]);
        }
    }
}

// ---------------- GRU gates + prep (zero ctx region, hid=bias, rsum=0) --------------
__global__ void k_gru(const float* __restrict__ gx, const float* __restrict__ gh,
                      const float* __restrict__ h0, const float* __restrict__ b_oh,
                      float* __restrict__ comb, float* __restrict__ hout,
                      float* __restrict__ hid, float* __restrict__ rsum) {
    int idx = blockIdx.x * blockDim.x + threadIdx.x;  // B*H2 = 65536
    int b = idx >> 9, h = idx & 511;
    const float* gxb = gx + b * H3_;
    const float* ghb = gh + b * H3_;
    float xr = gxb[h], xz = gxb[H2_ + h], xn = gxb[2 * H2_ + h];
    float hr = ghb[h], hz = ghb[H2_ + h], hn = ghb[2 * H2_ + h];
    float r = fast_sigmoid(xr + hr);
    float z = fast_sigmoid(xz + hz);
    float n = fast_tanh(xn + r * hn);
    float hv = (1.f - z) * n + z * h0[idx];
    comb[b * (2 * H2_) + h] = hv;
    comb[b * (2 * H2_) + H2_ + h] = 0.f;   // zero context slot
    hout[idx] = hv;
    if (idx < B_ * E_) hid[idx] = b_oh[idx & 127];  // split-K target init
    if (idx < B_) rsum[idx] = 0.f;
}

// ---------------- attention scores: one wave per (l,b) ----------------
__global__ void k_scores(const float* __restrict__ enc, const float* __restrict__ dsl,
                         const float* __restrict__ w_h, const float* __restrict__ att_v,
                         float* __restrict__ scores) {
    int wid = (blockIdx.x << 2) + (threadIdx.x >> 6);
    int lane = threadIdx.x & 63;
    int l = wid >> 7, b = wid & 127;
    const float4* e4 = (const float4*)(enc + ((size_t)(l * B_ + b)) * H2_);
    const float4* d4 = (const float4*)(dsl + b * H2_);
    const float4* w4 = (const float4*)w_h;
    const float4* v4 = (const float4*)att_v;
    float s = 0.f;
    #pragma unroll
    for (int i = 0; i < 2; ++i) {
        int j = lane + (i << 6);
        float4 e = e4[j], d = d4[j], w = w4[j], v = v4[j];
        s += v.x * fast_tanh(w.x * e.x + d.x);
        s += v.y * fast_tanh(w.y * e.y + d.y);
        s += v.z * fast_tanh(w.z * e.z + d.z);
        s += v.w * fast_tanh(w.w * e.w + d.w);
    }
    #pragma unroll
    for (int o = 32; o; o >>= 1) s += __shfl_xor(s, o);
    if (lane == 0) scores[l * B_ + b] = s;
}

// ---------------- softmax over batch axis (per l) ----------------
__global__ void k_softmax(const float* __restrict__ scores, float* __restrict__ attn) {
    int l = blockIdx.x, lane = threadIdx.x;   // 64 threads
    float s0 = scores[l * B_ + lane], s1 = scores[l * B_ + lane + 64];
    float m = fmaxf(s0, s1);
    #pragma unroll
    for (int o = 32; o; o >>= 1) m = fmaxf(m, __shfl_xor(m, o));
    float e0 = __expf(s0 - m), e1 = __expf(s1 - m);
    float t = e0 + e1;
    #pragma unroll
    for (int o = 32; o; o >>= 1) t += __shfl_xor(t, o);
    float inv = 1.f / t;
    attn[l * B_ + lane] = e0 * inv;
    attn[l * B_ + lane + 64] = e1 * inv;
}

// ---------------- context: block (b, l-chunk of 64), 512 threads over h ----------------
__global__ void k_context(const float* __restrict__ enc, const float* __restrict__ attn,
                          float* __restrict__ comb) {
    int b = blockIdx.x, h = threadIdx.x;
    int l0 = blockIdx.y << 6;
    __shared__ float a_s[64];
    if (threadIdx.x < 64) a_s[threadIdx.x] = attn[(l0 + threadIdx.x) * B_ + b];
    __syncthreads();
    const float* e = enc + ((size_t)l0 * B_ + b) * H2_ + h;
    float c = 0.f;
    #pragma unroll 8
    for (int i = 0; i < 64; ++i) c += a_s[i] * e[(size_t)i * B_ * H2_];
    atomicAdd(&comb[b * (2 * H2_) + H2_ + h], c);
}

// ---------------- p_gen: one wave per b ----------------
__global__ void k_pgen(const float* __restrict__ comb,
                       const int* __restrict__ ids, const float* __restrict__ tab,
                       const float* __restrict__ W_ptr, const float* __restrict__ b_ptr,
                       float* __restrict__ pgen) {
    int b = blockIdx.x, lane = threadIdx.x;  // 64 threads
    float s = 0.f;
    for (int j = lane; j < 2 * H2_; j += 64) s += W_ptr[j] * comb[b * (2 * H2_) + j];
    const float* erow = tab + (size_t)ids[b] * E_;
    for (int j = lane; j < E_; j += 64) s += W_ptr[2 * H2_ + j] * erow[j];
    #pragma unroll
    for (int o = 32; o; o >>= 1) s += __shfl_xor(s, o);
    if (lane == 0) pgen[b] = fast_sigmoid(s + b_ptr[0]);
}

// ---------------- vocab GEMM + exp epilogue + row-sum atomics ----------------
// out[m,n] = exp(A[m,:]·W[n,:] + bias[n]); rsum[m] += partials. A:[128,128] W:[V,128]
__global__ void k_vocab(const float* __restrict__ A, const float* __restrict__ W,
                        const float* __restrict__ bias, float* __restrict__ out,
                        float* __restrict__ rsum) {
    __shared__ float As[32][68];
    __shared__ float Ws[32][132];
    int bm = blockIdx.x * 64, bn = blockIdx.y * 128;
    int tid = threadIdx.x;
    int tm0 = (tid / 16) * 4;       // 16 row-groups of 4 rows
    int tn0 = (tid % 16) * 8;
    float acc[4][8] = {};
    for (int k0 = 0; k0 < 128; k0 += 32) {
        #pragma unroll
        for (int v = tid; v < 512; v += 256) {          // A: 64x32
            int m = v >> 3, q = (v & 7) << 2;
            float4 x = *(const float4*)(A + (bm + m) * 128 + k0 + q);
            As[q+0][m] = x.x; As[q+1][m] = x.y; As[q+2][m] = x.z; As[q+3][m] = x.w;
        }
        #pragma unroll
        for (int v = tid; v < 1024; v += 256) {         // W: 128x32
            int n = v >> 3, q = (v & 7) << 2;
            int gn = bn + n;
            float4 x = make_float4(0.f, 0.f, 0.f, 0.f);
            if (gn < V_) x = *(const float4*)(W + (size_t)gn * 128 + k0 + q);
            Ws[q+0][n] = x.x; Ws[q+1][n] = x.y; Ws[q+2][n] = x.z; Ws[q+3][n] = x.w;
        }
        __syncthreads();
        #pragma unroll
        for (int kk = 0; kk < 32; ++kk) {
            float a[4], w[8];
            #pragma unroll
            for (int i = 0; i < 4; ++i) a[i] = As[kk][tm0 + i];
            #pragma unroll
            for (int j = 0; j < 8; ++j) w[j] = Ws[kk][tn0 + j];
            #pragma unroll
            for (int i = 0; i < 4; ++i)
                #pragma unroll
                for (int j = 0; j < 8; ++j) acc[i][j] += a[i] * w[j];
        }
        __syncthreads();
    }
    // epilogue: exp + store + per-row partial sums
    float rs[4] = {0.f, 0.f, 0.f, 0.f};
    #pragma unroll
    for (int i = 0; i < 4; ++i) {
        int gm = bm + tm0 + i;
        #pragma unroll
        for (int jq = 0; jq < 2; ++jq) {                // two float4 chunks
            int gn = bn + tn0 + jq * 4;
            if (gn < V_) {                              // V_%4==0: chunk all-in or all-out
                float4 e;
                e.x = __expf(acc[i][jq*4+0] + bias[gn+0]);
                e.y = __expf(acc[i][jq*4+1] + bias[gn+1]);
                e.z = __expf(acc[i][jq*4+2] + bias[gn+2]);
                e.w = __expf(acc[i][jq*4+3] + bias[gn+3]);
                *(float4*)(out + (size_t)gm * VL_ + gn) = e;
                rs[i] += e.x + e.y + e.z + e.w;
            }
        }
    }
    #pragma unroll
    for (int o = 1; o < 16; o <<= 1) {
        #pragma unroll
        for (int i = 0; i < 4; ++i) rs[i] += __shfl_xor(rs[i], o);
    }
    if ((tid & 15) == 0) {
        #pragma unroll
        for (int i = 0; i < 4; ++i) atomicAdd(&rsum[bm + tm0 + i], rs[i]);
    }
}

// ---------------- finalize: scale by pgen/rsum, zero pad (float4) ----------------
__global__ void k_final(float* __restrict__ out, const float* __restrict__ pgen,
                        const float* __restrict__ rsum) {
    int idx = blockIdx.x * blockDim.x + threadIdx.x;   // B * VL/4
    if (idx >= B_ * (VL_ / 4)) return;
    int b = idx / (VL_ / 4);
    int j = idx - b * (VL_ / 4);
    float4* p = (float4*)(out) + idx;
    if (j < V_ / 4) {
        float sc = pgen[b] / rsum[b];
        float4 x = *p;
        x.x *= sc; x.y *= sc; x.z *= sc; x.w *= sc;
        *p = x;
    } else {
        *p = make_float4(0.f, 0.f, 0.f, 0.f);
    }
}

// ---------------- scatter copy distribution ----------------
__global__ void k_scatter(float* __restrict__ out, const int* __restrict__ full_input,
                          const float* __restrict__ attn, const float* __restrict__ pgen) {
    int idx = blockIdx.x * blockDim.x + threadIdx.x;  // L*B = 65536
    int b = idx & 127;
    int tok = full_input[idx];
    atomicAdd(&out[(size_t)b * VL_ + tok], (1.f - pgen[b]) * attn[idx]);
}

extern "C" void kernel_launch(void* const* d_in, const int* in_sizes, int n_in,
                              void* d_out, int out_size, void* d_ws, size_t ws_size,
                              hipStream_t stream) {
    const int*   input_ids = (const int*)d_in[0];
    const float* hidden    = (const float*)d_in[1];
    const float* enc       = (const float*)d_in[2];
    const int*   full_in   = (const int*)d_in[3];
    const float* emb_tab   = (const float*)d_in[4];
    const float* W_ih      = (const float*)d_in[5];
    const float* W_hh      = (const float*)d_in[6];
    const float* b_ih      = (const float*)d_in[7];
    const float* b_hh      = (const float*)d_in[8];
    const float* W_ds      = (const float*)d_in[9];
    const float* b_ds      = (const float*)d_in[10];
    const float* w_h       = (const float*)d_in[11];
    const float* att_v     = (const float*)d_in[12];
    const float* W_oh      = (const float*)d_in[13];
    const float* b_oh      = (const float*)d_in[14];
    const float* W_ov      = (const float*)d_in[15];
    const float* b_ov      = (const float*)d_in[16];
    const float* W_ptr     = (const float*)d_in[17];
    const float* b_ptr     = (const float*)d_in[18];

    float* out = (float*)d_out;
    float* p_final = out;                                  // [B, VL]
    float* h_out   = out + (size_t)B_ * VL_;               // [B, H2]
    float* attn    = out + (size_t)B_ * VL_ + B_ * H2_;    // [L, B]

    float* ws = (float*)d_ws;
    float* gx     = ws;            // 196608
    float* gh     = gx + 196608;   // 196608
    float* comb   = gh + 196608;   // 131072  [B, 2*H2]: h_new | context
    float* dsl    = comb + 131072; // 65536
    float* scores = dsl + 65536;   // 65536
    float* hid    = scores + 65536;// 16384
    float* pgen   = hid + 16384;   // 128
    float* rsum   = pgen + 128;    // 128

    // 1. gx = emb[ids] @ W_ih^T + b_ih   [128,1536] K=128
    gemm_t<32,32,32,2,2,true,1><<<dim3(4,48), dim3(256), 0, stream>>>(
        nullptr, E_, input_ids, emb_tab, W_ih, E_, b_ih, gx, H3_, H3_, E_);
    // 2. gh = h0 @ W_hh^T + b_hh        [128,1536] K=512
    gemm_t<32,32,32,2,2,false,1><<<dim3(4,48), dim3(256), 0, stream>>>(
        hidden, H2_, nullptr, nullptr, W_hh, H2_, b_hh, gh, H3_, H3_, H2_);
    // 3. GRU gates -> h_new; zero ctx, hid=bias, rsum=0
    k_gru<<<dim3(256), dim3(256), 0, stream>>>(gx, gh, hidden, b_oh, comb, h_out, hid, rsum);
    // 4. dsl = h_new @ W_ds^T + b_ds
    gemm_t<32,32,32,2,2,false,1><<<dim3(4,16), dim3(256), 0, stream>>>(
        comb, 2*H2_, nullptr, nullptr, W_ds, H2_, b_ds, dsl, H2_, H2_, H2_);
    // 5. attention scores
    k_scores<<<dim3(L_*B_/4), dim3(256), 0, stream>>>(enc, dsl, w_h, att_v, scores);
    // 6. softmax over batch axis
    k_softmax<<<dim3(L_), dim3(64), 0, stream>>>(scores, attn);
    // 7. context
    k_context<<<dim3(B_, 8), dim3(512), 0, stream>>>(enc, attn, comb);
    // 8. p_gen
    k_pgen<<<dim3(B_), dim3(64), 0, stream>>>(comb, input_ids, emb_tab, W_ptr, b_ptr, pgen);
    // 9. hid = comb @ W_oh^T (+b_oh via init), split-K 8
    gemm_t<32,32,32,2,2,false,8><<<dim3(4,4,8), dim3(256), 0, stream>>>(
        comb, 2*H2_, nullptr, nullptr, W_oh, 2*H2_, nullptr, hid, E_, E_, 2*H2_);
    // 10. p_final[:, :V] = exp(hid @ W_ov^T + b_ov); rsum row sums
    k_vocab<<<dim3(2,391), dim3(256), 0, stream>>>(hid, W_ov, b_ov, p_final, rsum);
    // 11. scale by pgen/rsum, zero pad
    k_final<<<dim3((B_*(VL_/4) + 255)/256), dim3(256), 0, stream>>>(p_final, pgen, rsum);
    // 12. scatter
    k_scatter<<<dim3(L_*B_/256), dim3(256), 0, stream>>>(p_final, full_in, attn, pgen);
}